// Round 2
// 648.362 us; speedup vs baseline: 1.0339x; 1.0339x over previous
//
#include <hip/hip_runtime.h>
#include <hip/hip_bf16.h>

// Problem constants
// B = 512, SHAPE = (64,64,64), RANKS = (8,8,8), SEP = 4
// x:       [512, 64,64,64] f32   (d_in[0], 134217728 elems, 512 MiB)
// core:    [8,8,8]        f32    (d_in[1], 512 elems)
// factors: [4, 3, 64, 8]  f32    (d_in[2], 6144 elems)
// out:     [512]          f32
// ws: 2 GiB (harness poison fill writes 2.147e9 B) -> partial buffer is safe.

typedef float fvec4 __attribute__((ext_vector_type(4)));

// ---------------------------------------------------------------------------
// Kernel 1: expand T[i,j,k] = sum_s sum_abc core[a,b,c] U1_s[i,a] U2_s[j,b] U3_s[k,c]
// One block per i (64 blocks, 256 threads). Mode-product chain per term s.
// ~10 us, not the bottleneck — unchanged.
// ---------------------------------------------------------------------------
__global__ __launch_bounds__(256) void tucker_expand_kernel(
    const float* __restrict__ core,
    const float* __restrict__ factors,
    float* __restrict__ T) {
  const int i = blockIdx.x;   // 0..63
  const int t = threadIdx.x;  // 0..255

  __shared__ float core_s[512];   // [a*64 + b*8 + c]
  __shared__ float c1[64];        // [b*8 + c]
  __shared__ float c2[512];       // [j*8 + c]
  __shared__ float u3[64 * 9];    // [k*9 + c], padded stride kills 4-bank alias

  core_s[t]       = core[t];
  core_s[t + 256] = core[t + 256];

  float tacc[16];
#pragma unroll
  for (int m = 0; m < 16; ++m) tacc[m] = 0.f;

  for (int s = 0; s < 4; ++s) {
    {
      const float* U3 = factors + ((s * 3 + 2) * 64) * 8;
      int e0 = t, e1 = t + 256;
      u3[(e0 >> 3) * 9 + (e0 & 7)] = U3[e0];
      u3[(e1 >> 3) * 9 + (e1 & 7)] = U3[e1];
    }
    __syncthreads();  // also covers core_s on s==0

    if (t < 64) {  // c1[b*8+c] = sum_a core[a,b,c] * U1[i,a]
      const float* U1row = factors + ((s * 3 + 0) * 64 + i) * 8;
      float v = 0.f;
#pragma unroll
      for (int a = 0; a < 8; ++a) v += core_s[a * 64 + t] * U1row[a];
      c1[t] = v;
    }
    __syncthreads();

    {  // c2[j*8+c] = sum_b U2[j,b] * c1[b*8+c]
      const float* U2 = factors + ((s * 3 + 1) * 64) * 8;
#pragma unroll
      for (int rep = 0; rep < 2; ++rep) {
        int e = t + rep * 256;
        int j = e >> 3, c = e & 7;
        float v = 0.f;
#pragma unroll
        for (int b = 0; b < 8; ++b) v += U2[j * 8 + b] * c1[b * 8 + c];
        c2[e] = v;
      }
    }
    __syncthreads();

#pragma unroll
    for (int m = 0; m < 16; ++m) {  // T slice accumulate, coalesced
      int e = m * 256 + t;
      int j = e >> 6, k = e & 63;
      float v = 0.f;
#pragma unroll
      for (int c = 0; c < 8; ++c) v += u3[k * 9 + c] * c2[j * 8 + c];
      tacc[m] += v;
    }
    __syncthreads();
  }

#pragma unroll
  for (int m = 0; m < 16; ++m) T[i * 4096 + m * 256 + t] = tacc[m];
}

// ---------------------------------------------------------------------------
// Kernel 2 (stage 1): 32-way split-K dot, 2 batches per block.
//   Block (bp, s): stage T-slice s (32 KB) into LDS once, stream x-slices of
//   batches 2*bp and 2*bp+1 (64 KB of x) against it.
//   - 8192 blocks x 256 threads; LDS exactly 32 KB -> 5 blocks/CU, 20 waves.
//   - Inner loop: 2 independent nt x-loads + 1 ds_read_b128 + 8 FMA; the HBM
//     stream never waits on L2 (T decoupled via LDS), 16 loads in flight/lane.
//   - nt on x keeps the dead stream from evicting T's lines in L2.
//   Deterministic: block partials -> ws, reduced by stage 2. No atomics.
// ---------------------------------------------------------------------------
__global__ __launch_bounds__(256) void dot_stage1(
    const float* __restrict__ x,
    const float* __restrict__ T,
    float* __restrict__ partial) {
  const int blk = blockIdx.x;     // 0..8191
  const int s   = blk & 31;       // slice 0..31
  const int bp  = blk >> 5;       // batch pair 0..255
  const int tid = threadIdx.x;    // 0..255

  __shared__ fvec4 Tl[2048];      // exactly 32 KB (no pad: keep 5 blocks/CU)

  const fvec4* tg = reinterpret_cast<const fvec4*>(T) + s * 2048;
#pragma unroll
  for (int k = 0; k < 8; ++k) Tl[k * 256 + tid] = tg[k * 256 + tid];
  __syncthreads();

  const fvec4* xg0 =
      reinterpret_cast<const fvec4*>(x) + (size_t)(bp * 2) * 65536 + s * 2048;
  const fvec4* xg1 = xg0 + 65536;

  float a0 = 0.f, a1 = 0.f, a2 = 0.f, a3 = 0.f;  // batch 2*bp
  float c0 = 0.f, c1 = 0.f, c2 = 0.f, c3 = 0.f;  // batch 2*bp+1
#pragma unroll
  for (int k = 0; k < 8; ++k) {
    fvec4 xv0 = __builtin_nontemporal_load(xg0 + k * 256 + tid);  // HBM stream
    fvec4 xv1 = __builtin_nontemporal_load(xg1 + k * 256 + tid);  // HBM stream
    fvec4 tv  = Tl[k * 256 + tid];                                // LDS
    a0 += xv0.x * tv.x; a1 += xv0.y * tv.y;
    a2 += xv0.z * tv.z; a3 += xv0.w * tv.w;
    c0 += xv1.x * tv.x; c1 += xv1.y * tv.y;
    c2 += xv1.z * tv.z; c3 += xv1.w * tv.w;
  }
  float s0 = (a0 + a1) + (a2 + a3);
  float s1 = (c0 + c1) + (c2 + c3);

  // wave-64 butterflies (both batches)
#pragma unroll
  for (int off = 32; off > 0; off >>= 1) {
    s0 += __shfl_down(s0, off, 64);
    s1 += __shfl_down(s1, off, 64);
  }

  // Cross-wave reduce via LDS scratch (Tl reads all done; barrier orders
  // them before the overwrite). LDS stays exactly 32 KB.
  __syncthreads();
  float* red = reinterpret_cast<float*>(Tl);
  const int wave = tid >> 6, lane = tid & 63;
  if (lane == 0) { red[wave] = s0; red[4 + wave] = s1; }
  __syncthreads();
  if (tid == 0) {
    partial[s * 512 + bp * 2]     = (red[0] + red[1]) + (red[2] + red[3]);
    partial[s * 512 + bp * 2 + 1] = (red[4] + red[5]) + (red[6] + red[7]);
  }
}

// ---------------------------------------------------------------------------
// Fallback stage 1 (only if ws can't hold the partial buffer): atomics into
// out, which zero_out clears first. Never expected to run (ws = 2 GiB).
// ---------------------------------------------------------------------------
__global__ __launch_bounds__(512) void zero_out(float* __restrict__ out) {
  out[threadIdx.x] = 0.f;
}

__global__ __launch_bounds__(256) void dot_stage1_atomic(
    const float* __restrict__ x,
    const float* __restrict__ T,
    float* __restrict__ out) {
  const int blk = blockIdx.x;
  const int s   = blk & 31;
  const int bp  = blk >> 5;
  const int tid = threadIdx.x;

  __shared__ fvec4 Tl[2048];
  const fvec4* tg = reinterpret_cast<const fvec4*>(T) + s * 2048;
#pragma unroll
  for (int k = 0; k < 8; ++k) Tl[k * 256 + tid] = tg[k * 256 + tid];
  __syncthreads();

  const fvec4* xg0 =
      reinterpret_cast<const fvec4*>(x) + (size_t)(bp * 2) * 65536 + s * 2048;
  const fvec4* xg1 = xg0 + 65536;

  float a0 = 0.f, a1 = 0.f, a2 = 0.f, a3 = 0.f;
  float c0 = 0.f, c1 = 0.f, c2 = 0.f, c3 = 0.f;
#pragma unroll
  for (int k = 0; k < 8; ++k) {
    fvec4 xv0 = __builtin_nontemporal_load(xg0 + k * 256 + tid);
    fvec4 xv1 = __builtin_nontemporal_load(xg1 + k * 256 + tid);
    fvec4 tv  = Tl[k * 256 + tid];
    a0 += xv0.x * tv.x; a1 += xv0.y * tv.y;
    a2 += xv0.z * tv.z; a3 += xv0.w * tv.w;
    c0 += xv1.x * tv.x; c1 += xv1.y * tv.y;
    c2 += xv1.z * tv.z; c3 += xv1.w * tv.w;
  }
  float s0 = (a0 + a1) + (a2 + a3);
  float s1 = (c0 + c1) + (c2 + c3);
#pragma unroll
  for (int off = 32; off > 0; off >>= 1) {
    s0 += __shfl_down(s0, off, 64);
    s1 += __shfl_down(s1, off, 64);
  }
  __syncthreads();
  float* red = reinterpret_cast<float*>(Tl);
  const int wave = tid >> 6, lane = tid & 63;
  if (lane == 0) { red[wave] = s0; red[4 + wave] = s1; }
  __syncthreads();
  if (tid == 0) {
    atomicAdd(&out[bp * 2],     (red[0] + red[1]) + (red[2] + red[3]));
    atomicAdd(&out[bp * 2 + 1], (red[4] + red[5]) + (red[6] + red[7]));
  }
}

// ---------------------------------------------------------------------------
// Kernel 3 (stage 2): out[b] = sum_s partial[s][b]. 64 KB from L2, coalesced
// per s-iteration. Deterministic fixed-order reduction.
// ---------------------------------------------------------------------------
__global__ __launch_bounds__(64) void dot_stage2(
    const float* __restrict__ partial,
    float* __restrict__ out) {
  const int b = blockIdx.x * 64 + threadIdx.x;  // 8 blocks x 64 threads = 512
  float v = 0.f;
#pragma unroll
  for (int s = 0; s < 32; ++s) v += partial[s * 512 + b];
  out[b] = v;
}

extern "C" void kernel_launch(void* const* d_in, const int* in_sizes, int n_in,
                              void* d_out, int out_size, void* d_ws, size_t ws_size,
                              hipStream_t stream) {
  const float* x       = (const float*)d_in[0];
  const float* core    = (const float*)d_in[1];
  const float* factors = (const float*)d_in[2];
  float* out = (float*)d_out;

  float* T = (float*)d_ws;  // 262144 f32 = 1 MiB

  tucker_expand_kernel<<<64, 256, 0, stream>>>(core, factors, T);

  const size_t need = (size_t)(262144 + 32 * 512) * sizeof(float);
  if (ws_size >= need) {
    // Deterministic two-stage path (expected: ws = 2 GiB).
    float* partial = T + 262144;  // 32*512 f32 = 64 KiB
    dot_stage1<<<8192, 256, 0, stream>>>(x, T, partial);
    dot_stage2<<<8, 64, 0, stream>>>(partial, out);
  } else {
    // Defensive fallback: never writes outside [d_ws, d_ws + 1 MiB).
    zero_out<<<1, 512, 0, stream>>>(out);
    dot_stage1_atomic<<<8192, 256, 0, stream>>>(x, T, out);
  }
}